// Round 11
// baseline (54.525 us; speedup 1.0000x reference)
//
#include <hip/hip_runtime.h>

#define NPG 1024
#define NG 64
#define KKEEP 512
#define DF 256
#define NTOT (NG * NPG)        // 65536 nodes
#define NROWS (NG * KKEEP)     // 32768 kept rows
#define EPG 32768              // edges per graph
#define NBD 4                  // deg partial blocks per graph
#define EPBD (EPG / NBD)       // 8192 edges per deg block
#define HI_ROWS 256
#define LO_ROWS (NROWS - HI_ROWS)
#define FXS 1099511627776.0    // 2^40 fixed-point scale
#define DOTS_BLOCKS (NTOT / 16)  // 4096: 16 nodes per 256-thread block

typedef float vf4 __attribute__((ext_vector_type(4)));
typedef int   vi4 __attribute__((ext_vector_type(4)));
typedef unsigned int vu4 __attribute__((ext_vector_type(4)));

// in-register bitonic compare-exchange via wave shuffle (j <= 32)
__device__ __forceinline__ unsigned long long cex(unsigned long long a, int t, int k, int j) {
    unsigned long long b = __shfl_xor(a, j, 64);
    bool lower = ((t & j) == 0);
    bool desc  = ((t & k) == 0);
    unsigned long long mn = a < b ? a : b;
    unsigned long long mx = a < b ? b : a;
    return (desc == lower) ? mx : mn;
}

// fused: blocks [0, DOTS_BLOCKS) = dots (4 nodes/wave, 16-lane groups);
//        blocks [DOTS_BLOCKS, +NG*NBD) = degree partials + packed-edge emit (NT raw reads)
__global__ __launch_bounds__(256) void k_front(const float* __restrict__ x,
                                               const float* __restrict__ w1,
                                               const float* __restrict__ wg,
                                               const int* __restrict__ rows,
                                               const int* __restrict__ cols,
                                               float* __restrict__ sc0,
                                               float* __restrict__ xwg,
                                               int* __restrict__ degp,
                                               unsigned int* __restrict__ ep) {
    __shared__ int deg_l[NPG];
    const int b = blockIdx.x;
    const int t = threadIdx.x;
    if (b < DOTS_BLOCKS) {
        const int lane = t & 63;
        const int grp  = lane & 15;              // element-group lane
        const int node = b * 16 + (t >> 6) * 4 + (lane >> 4);
        double s1 = 0.0, s2 = 0.0;
#pragma unroll
        for (int i = 0; i < 4; ++i) {
            const int off = grp * 4 + i * 64;
            const float4 xv = *reinterpret_cast<const float4*>(x + (size_t)node * DF + off);
            const float4 av = *reinterpret_cast<const float4*>(w1 + off);
            const float4 bv = *reinterpret_cast<const float4*>(wg + off);
            s1 += (double)xv.x * av.x + (double)xv.y * av.y + (double)xv.z * av.z + (double)xv.w * av.w;
            s2 += (double)xv.x * bv.x + (double)xv.y * bv.y + (double)xv.z * bv.z + (double)xv.w * bv.w;
        }
#pragma unroll
        for (int m = 1; m <= 8; m <<= 1) {
            s1 += __shfl_xor(s1, m);
            s2 += __shfl_xor(s2, m);
        }
        if (grp == 0) { sc0[node] = (float)s1; xwg[node] = (float)s2; }
    } else {
        const int bb = b - DOTS_BLOCKS;         // 0 .. NG*NBD-1
        const int g = bb >> 2, sub = bb & 3;
        deg_l[t] = 0; deg_l[t + 256] = 0; deg_l[t + 512] = 0; deg_l[t + 768] = 0;
        __syncthreads();
        const size_t e0 = (size_t)g * EPG + sub * EPBD;
        const vi4* r4 = reinterpret_cast<const vi4*>(rows + e0);
        const vi4* c4 = reinterpret_cast<const vi4*>(cols + e0);
        vu4* ep4 = reinterpret_cast<vu4*>(ep + e0);
#pragma unroll 2
        for (int i = t; i < EPBD / 4; i += 256) {
            vi4 r = __builtin_nontemporal_load(r4 + i);   // last use of raw edges
            vi4 c = __builtin_nontemporal_load(c4 + i);
            vu4 p;
            p.x = (((unsigned)r.x & (NPG - 1)) << 10) | ((unsigned)c.x & (NPG - 1));
            p.y = (((unsigned)r.y & (NPG - 1)) << 10) | ((unsigned)c.y & (NPG - 1));
            p.z = (((unsigned)r.z & (NPG - 1)) << 10) | ((unsigned)c.z & (NPG - 1));
            p.w = (((unsigned)r.w & (NPG - 1)) << 10) | ((unsigned)c.w & (NPG - 1));
            ep4[i] = p;
            if (r.x != c.x) atomicAdd(&deg_l[p.x & (NPG - 1)], 1);
            if (r.y != c.y) atomicAdd(&deg_l[p.y & (NPG - 1)], 1);
            if (r.z != c.z) atomicAdd(&deg_l[p.z & (NPG - 1)], 1);
            if (r.w != c.w) atomicAdd(&deg_l[p.w & (NPG - 1)], 1);
        }
        __syncthreads();
        int* dst = degp + (size_t)bb * NPG;
        dst[t] = deg_l[t]; dst[t + 256] = deg_l[t + 256];
        dst[t + 512] = deg_l[t + 512]; dst[t + 768] = deg_l[t + 768];
    }
}

// one block per graph: dis from deg partials -> gcn scatter (LDS u64 fixed-point, full graph)
// -> score -> hybrid bitonic sort -> node_map + rowinfo. No global partials round-trip.
__global__ __launch_bounds__(1024) void k_gs(const unsigned int* __restrict__ ep,
                                             const int* __restrict__ degp,
                                             const float* __restrict__ xwg,
                                             const float* __restrict__ sc0,
                                             const float* __restrict__ b1,
                                             const float* __restrict__ bg,
                                             int* __restrict__ node_map,
                                             int2* __restrict__ rowinfo) {
    __shared__ float dis_l[NPG];
    __shared__ float dxw_l[NPG];                 // dis[t] * xwg[t]
    __shared__ unsigned long long gcn_l[NPG];    // gcn accumulators, then reused as sort keys
    __shared__ float score_l[NPG];
    const int g = blockIdx.x, t = threadIdx.x;
    const int nbase = g * NPG;
    {
        int d = degp[(size_t)(g * NBD + 0) * NPG + t] + degp[(size_t)(g * NBD + 1) * NPG + t]
              + degp[(size_t)(g * NBD + 2) * NPG + t] + degp[(size_t)(g * NBD + 3) * NPG + t];
        float dis = (d > 0) ? (1.0f / sqrtf((float)d)) : 0.0f;
        dis_l[t] = dis;
        dxw_l[t] = dis * xwg[nbase + t];
    }
    gcn_l[t] = 0;
    __syncthreads();
    const vu4* ep4 = reinterpret_cast<const vu4*>(ep + (size_t)g * EPG);
    for (int i = t; i < EPG / 4; i += 1024) {
        vu4 p = ep4[i];
        int rl, cl; float term;
        rl = (p.x >> 10) & (NPG - 1); cl = p.x & (NPG - 1);
        if (rl != cl) { term = dxw_l[rl] * dis_l[cl];
            atomicAdd(&gcn_l[cl], (unsigned long long)(long long)llrint((double)term * FXS)); }
        rl = (p.y >> 10) & (NPG - 1); cl = p.y & (NPG - 1);
        if (rl != cl) { term = dxw_l[rl] * dis_l[cl];
            atomicAdd(&gcn_l[cl], (unsigned long long)(long long)llrint((double)term * FXS)); }
        rl = (p.z >> 10) & (NPG - 1); cl = p.z & (NPG - 1);
        if (rl != cl) { term = dxw_l[rl] * dis_l[cl];
            atomicAdd(&gcn_l[cl], (unsigned long long)(long long)llrint((double)term * FXS)); }
        rl = (p.w >> 10) & (NPG - 1); cl = p.w & (NPG - 1);
        if (rl != cl) { term = dxw_l[rl] * dis_l[cl];
            atomicAdd(&gcn_l[cl], (unsigned long long)(long long)llrint((double)term * FXS)); }
    }
    __syncthreads();
    unsigned long long key;
    {
        float s2 = (float)((double)(long long)gcn_l[t] * (1.0 / FXS)) + bg[0];
        float s1 = sc0[nbase + t] + b1[0];
        float s = 0.5f * s1 + 0.5f * s2;
        score_l[t] = s;
        unsigned u = __float_as_uint(s);
        u = (u & 0x80000000u) ? ~u : (u | 0x80000000u);
        key = ((unsigned long long)u << 32) | (unsigned long long)(0xFFFFFFFFu - (unsigned)t);
    }
    // k = 2..64: intra-wave, registers + shuffles, zero barriers
#pragma unroll
    for (int k = 2; k <= 64; k <<= 1)
        for (int j = k >> 1; j > 0; j >>= 1)
            key = cex(key, t, k, j);
    gcn_l[t] = key;                 // own-slot write; atomic phase already barriered
    __syncthreads();
    // k = 128..1024: LDS steps for j>=64, shuffle tail for j<=32
    for (int k = 128; k <= NPG; k <<= 1) {
        for (int j = k >> 1; j >= 64; j >>= 1) {
            int ixj = t ^ j;
            if (ixj > t) {
                unsigned long long a = gcn_l[t], b = gcn_l[ixj];
                bool desc = ((t & k) == 0);
                if (desc ? (a < b) : (a > b)) { gcn_l[t] = b; gcn_l[ixj] = a; }
            }
            __syncthreads();
        }
        key = gcn_l[t];
#pragma unroll
        for (int j = 32; j > 0; j >>= 1)
            key = cex(key, t, k, j);
        if (k < NPG) { gcn_l[t] = key; __syncthreads(); }
    }
    int idx = (int)(0xFFFFFFFFu - (unsigned)(key & 0xFFFFFFFFull)) & (NPG - 1);
    if (t < KKEEP) {
        int row = g * KKEEP + t;
        node_map[nbase + idx] = row;
        rowinfo[row] = make_int2(nbase + idx, __float_as_int(tanhf(score_l[idx])));
    } else {
        node_map[nbase + idx] = -1;
    }
}

// edge relabel for vu4 index i from PACKED edges (graph id = i >> 13)
__device__ __forceinline__ void edge_body_packed(const unsigned int* __restrict__ ep,
                                                 const int* __restrict__ node_map,
                                                 float* __restrict__ oute, int E, int i) {
    const int* nm = node_map + (i >> 13) * NPG;   // EPG/4 = 8192 vu4 per graph
    vu4 p = __builtin_nontemporal_load(reinterpret_cast<const vu4*>(ep) + i);
    int ex = nm[(p.x >> 10) & (NPG - 1)], fx = nm[p.x & (NPG - 1)];
    int ey = nm[(p.y >> 10) & (NPG - 1)], fy = nm[p.y & (NPG - 1)];
    int ez = nm[(p.z >> 10) & (NPG - 1)], fz = nm[p.z & (NPG - 1)];
    int ew = nm[(p.w >> 10) & (NPG - 1)], fw = nm[p.w & (NPG - 1)];
    vf4 orow, ocol;
    orow.x = (ex >= 0 && fx >= 0) ? (float)ex : -1.0f;  ocol.x = (ex >= 0 && fx >= 0) ? (float)fx : -1.0f;
    orow.y = (ey >= 0 && fy >= 0) ? (float)ey : -1.0f;  ocol.y = (ey >= 0 && fy >= 0) ? (float)fy : -1.0f;
    orow.z = (ez >= 0 && fz >= 0) ? (float)ez : -1.0f;  ocol.z = (ez >= 0 && fz >= 0) ? (float)fz : -1.0f;
    orow.w = (ew >= 0 && fw >= 0) ? (float)ew : -1.0f;  ocol.w = (ew >= 0 && fw >= 0) ? (float)fw : -1.0f;
    __builtin_nontemporal_store(orow, reinterpret_cast<vf4*>(oute) + i);
    __builtin_nontemporal_store(ocol, reinterpret_cast<vf4*>(oute + (size_t)E) + i);
}

// edge relabel from RAW edges (fallback when packed array would race)
__device__ __forceinline__ void edge_body_raw(const int* __restrict__ rows,
                                              const int* __restrict__ cols,
                                              const int* __restrict__ node_map,
                                              float* __restrict__ oute, int E, int i) {
    vi4 r = __builtin_nontemporal_load(reinterpret_cast<const vi4*>(rows) + i);
    vi4 c = __builtin_nontemporal_load(reinterpret_cast<const vi4*>(cols) + i);
    int ex = node_map[r.x & (NTOT - 1)], fx = node_map[c.x & (NTOT - 1)];
    int ey = node_map[r.y & (NTOT - 1)], fy = node_map[c.y & (NTOT - 1)];
    int ez = node_map[r.z & (NTOT - 1)], fz = node_map[c.z & (NTOT - 1)];
    int ew = node_map[r.w & (NTOT - 1)], fw = node_map[c.w & (NTOT - 1)];
    vf4 orow, ocol;
    orow.x = (ex >= 0 && fx >= 0) ? (float)ex : -1.0f;  ocol.x = (ex >= 0 && fx >= 0) ? (float)fx : -1.0f;
    orow.y = (ey >= 0 && fy >= 0) ? (float)ey : -1.0f;  ocol.y = (ey >= 0 && fy >= 0) ? (float)fy : -1.0f;
    orow.z = (ez >= 0 && fz >= 0) ? (float)ez : -1.0f;  ocol.z = (ez >= 0 && fz >= 0) ? (float)fz : -1.0f;
    orow.w = (ew >= 0 && fw >= 0) ? (float)ew : -1.0f;  ocol.w = (ew >= 0 && fw >= 0) ? (float)fw : -1.0f;
    __builtin_nontemporal_store(orow, reinterpret_cast<vf4*>(oute) + i);
    __builtin_nontemporal_store(ocol, reinterpret_cast<vf4*>(oute + (size_t)E) + i);
}

__device__ __forceinline__ void gather_row(const float* __restrict__ x, int2 ri, int row,
                                           float* __restrict__ outx, float* __restrict__ outb,
                                           int lane) {
    float tg = __int_as_float(ri.y);
    const float4 v = *reinterpret_cast<const float4*>(x + (size_t)(ri.x & (NTOT - 1)) * DF + lane * 4);
    vf4 o;
    o.x = v.x * tg; o.y = v.y * tg; o.z = v.z * tg; o.w = v.w * tg;
    __builtin_nontemporal_store(o, reinterpret_cast<vf4*>(outx + (size_t)row * DF) + lane);
    if (lane == 0) __builtin_nontemporal_store((float)(row >> 9), outb + row);
}

// fused output (tier 1): blocks [0, NROWS/4) = gather; rest = edge relabel (packed or raw)
__global__ __launch_bounds__(256) void k_out(const float* __restrict__ x,
                                             const unsigned int* __restrict__ ep,
                                             const int* __restrict__ rows,
                                             const int* __restrict__ cols,
                                             const int* __restrict__ node_map,
                                             const int2* __restrict__ rowinfo,
                                             float* __restrict__ outx,
                                             float* __restrict__ oute,
                                             float* __restrict__ outb, int E) {
    const int b = blockIdx.x, t = threadIdx.x;
    if (b < NROWS / 4) {
        int row = b * 4 + (t >> 6);
        gather_row(x, rowinfo[row], row, outx, outb, t & 63);
    } else {
        int i = (b - NROWS / 4) * 256 + t;
        if (i < E / 4) {
            if (ep) edge_body_packed(ep, node_map, oute, E, i);
            else    edge_body_raw(rows, cols, node_map, oute, E, i);
        }
    }
}

// standalone edge kernel (fallback tiers; ep safe here — consumed before gather launches)
__global__ __launch_bounds__(256) void k_edges(const unsigned int* __restrict__ ep,
                                               const int* __restrict__ node_map,
                                               float* __restrict__ oute, int E) {
    int i = blockIdx.x * blockDim.x + threadIdx.x;
    if (i < E / 4) edge_body_packed(ep, node_map, oute, E, i);
}

// uniform gather (tiers 1-2), or rows [0, LO_ROWS) in tier 3
__global__ __launch_bounds__(256) void k_gather(const float* __restrict__ x,
                                                const int2* __restrict__ rowinfo,
                                                float* __restrict__ outx,
                                                float* __restrict__ outb) {
    int row = blockIdx.x * 4 + (threadIdx.x >> 6);
    gather_row(x, rowinfo[row], row, outx, outb, threadIdx.x & 63);
}

// tier-3 tail: single workgroup, stages rowinfo tail in LDS before overwriting it
__global__ __launch_bounds__(1024) void k_gather_hi(const float* __restrict__ x,
                                                    const int2* __restrict__ rowinfo,
                                                    float* __restrict__ outx,
                                                    float* __restrict__ outb) {
    __shared__ int2 info[HI_ROWS];
    int tid = threadIdx.x;
    if (tid < HI_ROWS) info[tid] = rowinfo[LO_ROWS + tid];
    __syncthreads();
    for (int it = tid; it < HI_ROWS * 64; it += 1024) {
        int rl = it >> 6, lane = it & 63;
        gather_row(x, info[rl], LO_ROWS + rl, outx, outb, lane);
    }
}

extern "C" void kernel_launch(void* const* d_in, const int* in_sizes, int n_in,
                              void* d_out, int out_size, void* d_ws, size_t ws_size,
                              hipStream_t stream) {
    const float* x = (const float*)d_in[0];
    const int* ei = (const int*)d_in[1];
    const float* w1 = (const float*)d_in[3];
    const float* b1 = (const float*)d_in[4];
    const float* wg = (const float*)d_in[5];
    const float* bg = (const float*)d_in[6];

    const int N = in_sizes[0] / DF;        // 65536
    const int E = in_sizes[1] / 2;         // 2097152
    const int* rows = ei;
    const int* cols = ei + E;

    // FLOAT32 outputs: x_new [32768*256] | new_edge_index [2*E] | batch_new [32768]
    float* outx = (float*)d_out;
    float* oute = outx + (size_t)NROWS * DF;
    float* outb = oute + (size_t)2 * E;

    // Scratch in the front of the x_new region (all consumed before gather overwrites it):
    // sc0 256K | xwg 256K | degp 1M | [ep 8M | node_map 256K]
    char* sb = (char*)d_out;
    float* sc0  = (float*)(sb + 0);                      //   0 .. 256K
    float* xwg  = (float*)(sb + (1 << 18));              // 256K .. 512K
    int*   degp = (int*)(sb + (2 << 18));                // 512K .. 1.5M

    const size_t EPBYTES = (size_t)E * 4;   // 8 MB packed edges
    int tier;
    int*  node_map;
    int2* rowinfo;
    unsigned int* ep;        // where the deg pass writes packed edges
    unsigned int* ep_out;    // what the output-stage edge relabel reads (null -> raw)
    if (ws_size >= (size_t)NTOT * 4 + (size_t)NROWS * 8 + EPBYTES) {
        tier = 1;                                     // everything in ws; fused k_out, packed
        node_map = (int*)d_ws;
        rowinfo  = (int2*)((char*)d_ws + (size_t)NTOT * 4);
        ep       = (unsigned int*)((char*)d_ws + (size_t)NTOT * 4 + (size_t)NROWS * 8);
        ep_out   = ep;
    } else if (ws_size >= (size_t)NTOT * 4 + (size_t)NROWS * 8) {
        tier = 1;                                     // fused k_out, but raw edges (ep would race)
        node_map = (int*)d_ws;
        rowinfo  = (int2*)((char*)d_ws + (size_t)NTOT * 4);
        ep       = (unsigned int*)(sb + (6 << 18));   // 1.5M .. 9.5M (pre-output use only)
        ep_out   = nullptr;
    } else if (ws_size >= (size_t)NROWS * 8) {
        tier = 2;
        node_map = (int*)(sb + (38 << 18));           // 9.5M .. 9.75M
        rowinfo  = (int2*)d_ws;
        ep       = (unsigned int*)(sb + (6 << 18));
        ep_out   = ep;                                // k_edges consumes before k_gather
    } else {
        tier = 3;
        node_map = (int*)(sb + (38 << 18));
        rowinfo  = (int2*)(sb + (size_t)NROWS * DF * 4 - (size_t)NROWS * 8);  // last 256K
        ep       = (unsigned int*)(sb + (6 << 18));
        ep_out   = ep;
    }

    hipLaunchKernelGGL(k_front, dim3(DOTS_BLOCKS + NG * NBD), dim3(256), 0, stream,
                       x, w1, wg, rows, cols, sc0, xwg, degp, ep);
    hipLaunchKernelGGL(k_gs, dim3(NG), dim3(1024), 0, stream,
                       ep, degp, xwg, sc0, b1, bg, node_map, rowinfo);
    if (tier == 1) {
        hipLaunchKernelGGL(k_out, dim3(NROWS / 4 + E / 4 / 256), dim3(256), 0, stream,
                           x, ep_out, rows, cols, node_map, rowinfo, outx, oute, outb, E);
    } else if (tier == 2) {
        hipLaunchKernelGGL(k_edges, dim3(E / 4 / 256), dim3(256), 0, stream, ep_out, node_map, oute, E);
        hipLaunchKernelGGL(k_gather, dim3(NROWS / 4), dim3(256), 0, stream, x, rowinfo, outx, outb);
    } else {
        hipLaunchKernelGGL(k_edges, dim3(E / 4 / 256), dim3(256), 0, stream, ep_out, node_map, oute, E);
        hipLaunchKernelGGL(k_gather, dim3(LO_ROWS / 4), dim3(256), 0, stream, x, rowinfo, outx, outb);
        hipLaunchKernelGGL(k_gather_hi, dim3(1), dim3(1024), 0, stream, x, rowinfo, outx, outb);
    }
}

// Round 12
// 52.069 us; speedup vs baseline: 1.0472x; 1.0472x over previous
//
#include <hip/hip_runtime.h>

#define NPG 1024
#define NG 64
#define KKEEP 512
#define DF 256
#define NTOT (NG * NPG)        // 65536 nodes
#define NROWS (NG * KKEEP)     // 32768 kept rows
#define EPG 32768              // edges per graph
#define NBD 4                  // deg partial blocks per graph
#define EPBD (EPG / NBD)       // 8192 edges per deg block
#define NB 8                   // gcn blocks per graph
#define EPB (EPG / NB)         // 4096 edges per gcn block
#define HI_ROWS 256
#define LO_ROWS (NROWS - HI_ROWS)
#define FXS 1099511627776.0    // 2^40 fixed-point scale
#define DEG_BLOCKS (NG * NBD)    // 256, dispatched FIRST to overlap with dots stream
#define DOTS_BLOCKS (NTOT / 16)  // 4096: 16 nodes per 256-thread block

typedef float vf4 __attribute__((ext_vector_type(4)));
typedef int   vi4 __attribute__((ext_vector_type(4)));
typedef unsigned int vu4 __attribute__((ext_vector_type(4)));

// in-register bitonic compare-exchange via wave shuffle (j <= 32)
__device__ __forceinline__ unsigned long long cex(unsigned long long a, int t, int k, int j) {
    unsigned long long b = __shfl_xor(a, j, 64);
    bool lower = ((t & j) == 0);
    bool desc  = ((t & k) == 0);
    unsigned long long mn = a < b ? a : b;
    unsigned long long mx = a < b ? b : a;
    return (desc == lower) ? mx : mn;
}

// fused: blocks [0, DEG_BLOCKS) = degree partials + packed-edge emit (dispatched first,
//        overlaps with dots); blocks [DEG_BLOCKS, +DOTS_BLOCKS) = dots (4 nodes/wave)
__global__ __launch_bounds__(256) void k_front(const float* __restrict__ x,
                                               const float* __restrict__ w1,
                                               const float* __restrict__ wg,
                                               const int* __restrict__ rows,
                                               const int* __restrict__ cols,
                                               float* __restrict__ sc0,
                                               float* __restrict__ xwg,
                                               int* __restrict__ degp,
                                               unsigned int* __restrict__ ep) {
    __shared__ int deg_l[NPG];
    const int b = blockIdx.x;
    const int t = threadIdx.x;
    if (b >= DEG_BLOCKS) {
        const int lane = t & 63;
        const int grp  = lane & 15;              // element-group lane
        const int node = (b - DEG_BLOCKS) * 16 + (t >> 6) * 4 + (lane >> 4);
        double s1 = 0.0, s2 = 0.0;
#pragma unroll
        for (int i = 0; i < 4; ++i) {
            const int off = grp * 4 + i * 64;
            const float4 xv = *reinterpret_cast<const float4*>(x + (size_t)node * DF + off);
            const float4 av = *reinterpret_cast<const float4*>(w1 + off);
            const float4 bv = *reinterpret_cast<const float4*>(wg + off);
            s1 += (double)xv.x * av.x + (double)xv.y * av.y + (double)xv.z * av.z + (double)xv.w * av.w;
            s2 += (double)xv.x * bv.x + (double)xv.y * bv.y + (double)xv.z * bv.z + (double)xv.w * bv.w;
        }
#pragma unroll
        for (int m = 1; m <= 8; m <<= 1) {
            s1 += __shfl_xor(s1, m);
            s2 += __shfl_xor(s2, m);
        }
        if (grp == 0) { sc0[node] = (float)s1; xwg[node] = (float)s2; }
    } else {
        const int bb = b;                       // 0 .. NG*NBD-1
        const int g = bb >> 2, sub = bb & 3;
        deg_l[t] = 0; deg_l[t + 256] = 0; deg_l[t + 512] = 0; deg_l[t + 768] = 0;
        __syncthreads();
        const size_t e0 = (size_t)g * EPG + sub * EPBD;
        const vi4* r4 = reinterpret_cast<const vi4*>(rows + e0);
        const vi4* c4 = reinterpret_cast<const vi4*>(cols + e0);
        vu4* ep4 = reinterpret_cast<vu4*>(ep + e0);
#pragma unroll 2
        for (int i = t; i < EPBD / 4; i += 256) {
            vi4 r = __builtin_nontemporal_load(r4 + i);   // last use of raw edges
            vi4 c = __builtin_nontemporal_load(c4 + i);
            vu4 p;
            p.x = (((unsigned)r.x & (NPG - 1)) << 10) | ((unsigned)c.x & (NPG - 1));
            p.y = (((unsigned)r.y & (NPG - 1)) << 10) | ((unsigned)c.y & (NPG - 1));
            p.z = (((unsigned)r.z & (NPG - 1)) << 10) | ((unsigned)c.z & (NPG - 1));
            p.w = (((unsigned)r.w & (NPG - 1)) << 10) | ((unsigned)c.w & (NPG - 1));
            ep4[i] = p;
            if (r.x != c.x) atomicAdd(&deg_l[p.x & (NPG - 1)], 1);
            if (r.y != c.y) atomicAdd(&deg_l[p.y & (NPG - 1)], 1);
            if (r.z != c.z) atomicAdd(&deg_l[p.z & (NPG - 1)], 1);
            if (r.w != c.w) atomicAdd(&deg_l[p.w & (NPG - 1)], 1);
        }
        __syncthreads();
        int* dst = degp + (size_t)bb * NPG;
        dst[t] = deg_l[t]; dst[t + 256] = deg_l[t + 256];
        dst[t + 512] = deg_l[t + 512]; dst[t + 768] = deg_l[t + 768];
    }
}

// NB blocks/graph: dis from deg partials; LDS u64 fixed-point gcn scatter; store partials
__global__ __launch_bounds__(1024) void k_gcn(const unsigned int* __restrict__ ep,
                                              const int* __restrict__ degp,
                                              const float* __restrict__ xwg,
                                              unsigned long long* __restrict__ gcnp) {
    __shared__ float dis_l[NPG];
    __shared__ float dxw_l[NPG];    // dis[t] * xwg[t]
    __shared__ unsigned long long gcn_l[NPG];
    const int t = threadIdx.x;
    const int g = blockIdx.x >> 3, sub = blockIdx.x & 7;
    {
        int d = degp[(size_t)(g * NBD + 0) * NPG + t] + degp[(size_t)(g * NBD + 1) * NPG + t]
              + degp[(size_t)(g * NBD + 2) * NPG + t] + degp[(size_t)(g * NBD + 3) * NPG + t];
        float dis = (d > 0) ? (1.0f / sqrtf((float)d)) : 0.0f;
        dis_l[t] = dis;
        dxw_l[t] = dis * xwg[g * NPG + t];
    }
    gcn_l[t] = 0;
    __syncthreads();
    const vu4* ep4 = reinterpret_cast<const vu4*>(ep + (size_t)g * EPG + sub * EPB);
    for (int i = t; i < EPB / 4; i += 1024) {
        vu4 p = ep4[i];
        int rl, cl; float term;
        rl = (p.x >> 10) & (NPG - 1); cl = p.x & (NPG - 1);
        if (rl != cl) { term = dxw_l[rl] * dis_l[cl];
            atomicAdd(&gcn_l[cl], (unsigned long long)(long long)llrint((double)term * FXS)); }
        rl = (p.y >> 10) & (NPG - 1); cl = p.y & (NPG - 1);
        if (rl != cl) { term = dxw_l[rl] * dis_l[cl];
            atomicAdd(&gcn_l[cl], (unsigned long long)(long long)llrint((double)term * FXS)); }
        rl = (p.z >> 10) & (NPG - 1); cl = p.z & (NPG - 1);
        if (rl != cl) { term = dxw_l[rl] * dis_l[cl];
            atomicAdd(&gcn_l[cl], (unsigned long long)(long long)llrint((double)term * FXS)); }
        rl = (p.w >> 10) & (NPG - 1); cl = p.w & (NPG - 1);
        if (rl != cl) { term = dxw_l[rl] * dis_l[cl];
            atomicAdd(&gcn_l[cl], (unsigned long long)(long long)llrint((double)term * FXS)); }
    }
    __syncthreads();
    gcnp[(size_t)blockIdx.x * NPG + t] = gcn_l[t];
}

// one block per graph: score -> hybrid bitonic (shuffle j<=32, LDS j>=64) -> node_map + rowinfo
__global__ __launch_bounds__(1024) void k_sort(const float* __restrict__ sc0,
                                               const unsigned long long* __restrict__ gcnp,
                                               const float* __restrict__ b1,
                                               const float* __restrict__ bg,
                                               int* __restrict__ node_map,
                                               int2* __restrict__ rowinfo) {
    __shared__ unsigned long long keys[NPG];
    __shared__ float score_l[NPG];
    const int g = blockIdx.x, t = threadIdx.x;
    const int nbase = g * NPG;
    unsigned long long key;
    {
        long long q = 0;
#pragma unroll
        for (int p = 0; p < NB; ++p) q += (long long)gcnp[(size_t)(g * NB + p) * NPG + t];
        float s2 = (float)((double)q * (1.0 / FXS)) + bg[0];
        float s1 = sc0[nbase + t] + b1[0];
        float s = 0.5f * s1 + 0.5f * s2;
        score_l[t] = s;
        unsigned u = __float_as_uint(s);
        u = (u & 0x80000000u) ? ~u : (u | 0x80000000u);
        key = ((unsigned long long)u << 32) | (unsigned long long)(0xFFFFFFFFu - (unsigned)t);
    }
#pragma unroll
    for (int k = 2; k <= 64; k <<= 1)
        for (int j = k >> 1; j > 0; j >>= 1)
            key = cex(key, t, k, j);
    keys[t] = key;
    __syncthreads();
    for (int k = 128; k <= NPG; k <<= 1) {
        for (int j = k >> 1; j >= 64; j >>= 1) {
            int ixj = t ^ j;
            if (ixj > t) {
                unsigned long long a = keys[t], b = keys[ixj];
                bool desc = ((t & k) == 0);
                if (desc ? (a < b) : (a > b)) { keys[t] = b; keys[ixj] = a; }
            }
            __syncthreads();
        }
        key = keys[t];
#pragma unroll
        for (int j = 32; j > 0; j >>= 1)
            key = cex(key, t, k, j);
        if (k < NPG) { keys[t] = key; __syncthreads(); }
    }
    int idx = (int)(0xFFFFFFFFu - (unsigned)(key & 0xFFFFFFFFull)) & (NPG - 1);
    if (t < KKEEP) {
        int row = g * KKEEP + t;
        node_map[nbase + idx] = row;
        rowinfo[row] = make_int2(nbase + idx, __float_as_int(tanhf(score_l[idx])));
    } else {
        node_map[nbase + idx] = -1;
    }
}

// edge relabel for vu4 index i from PACKED edges (graph id = i >> 13)
__device__ __forceinline__ void edge_body_packed(const unsigned int* __restrict__ ep,
                                                 const int* __restrict__ node_map,
                                                 float* __restrict__ oute, int E, int i) {
    const int* nm = node_map + (i >> 13) * NPG;   // EPG/4 = 8192 vu4 per graph
    vu4 p = __builtin_nontemporal_load(reinterpret_cast<const vu4*>(ep) + i);
    int ex = nm[(p.x >> 10) & (NPG - 1)], fx = nm[p.x & (NPG - 1)];
    int ey = nm[(p.y >> 10) & (NPG - 1)], fy = nm[p.y & (NPG - 1)];
    int ez = nm[(p.z >> 10) & (NPG - 1)], fz = nm[p.z & (NPG - 1)];
    int ew = nm[(p.w >> 10) & (NPG - 1)], fw = nm[p.w & (NPG - 1)];
    vf4 orow, ocol;
    orow.x = (ex >= 0 && fx >= 0) ? (float)ex : -1.0f;  ocol.x = (ex >= 0 && fx >= 0) ? (float)fx : -1.0f;
    orow.y = (ey >= 0 && fy >= 0) ? (float)ey : -1.0f;  ocol.y = (ey >= 0 && fy >= 0) ? (float)fy : -1.0f;
    orow.z = (ez >= 0 && fz >= 0) ? (float)ez : -1.0f;  ocol.z = (ez >= 0 && fz >= 0) ? (float)fz : -1.0f;
    orow.w = (ew >= 0 && fw >= 0) ? (float)ew : -1.0f;  ocol.w = (ew >= 0 && fw >= 0) ? (float)fw : -1.0f;
    __builtin_nontemporal_store(orow, reinterpret_cast<vf4*>(oute) + i);
    __builtin_nontemporal_store(ocol, reinterpret_cast<vf4*>(oute + (size_t)E) + i);
}

// edge relabel from RAW edges (fallback when packed array would race)
__device__ __forceinline__ void edge_body_raw(const int* __restrict__ rows,
                                              const int* __restrict__ cols,
                                              const int* __restrict__ node_map,
                                              float* __restrict__ oute, int E, int i) {
    vi4 r = __builtin_nontemporal_load(reinterpret_cast<const vi4*>(rows) + i);
    vi4 c = __builtin_nontemporal_load(reinterpret_cast<const vi4*>(cols) + i);
    int ex = node_map[r.x & (NTOT - 1)], fx = node_map[c.x & (NTOT - 1)];
    int ey = node_map[r.y & (NTOT - 1)], fy = node_map[c.y & (NTOT - 1)];
    int ez = node_map[r.z & (NTOT - 1)], fz = node_map[c.z & (NTOT - 1)];
    int ew = node_map[r.w & (NTOT - 1)], fw = node_map[c.w & (NTOT - 1)];
    vf4 orow, ocol;
    orow.x = (ex >= 0 && fx >= 0) ? (float)ex : -1.0f;  ocol.x = (ex >= 0 && fx >= 0) ? (float)fx : -1.0f;
    orow.y = (ey >= 0 && fy >= 0) ? (float)ey : -1.0f;  ocol.y = (ey >= 0 && fy >= 0) ? (float)fy : -1.0f;
    orow.z = (ez >= 0 && fz >= 0) ? (float)ez : -1.0f;  ocol.z = (ez >= 0 && fz >= 0) ? (float)fz : -1.0f;
    orow.w = (ew >= 0 && fw >= 0) ? (float)ew : -1.0f;  ocol.w = (ew >= 0 && fw >= 0) ? (float)fw : -1.0f;
    __builtin_nontemporal_store(orow, reinterpret_cast<vf4*>(oute) + i);
    __builtin_nontemporal_store(ocol, reinterpret_cast<vf4*>(oute + (size_t)E) + i);
}

__device__ __forceinline__ void gather_row(const float* __restrict__ x, int2 ri, int row,
                                           float* __restrict__ outx, float* __restrict__ outb,
                                           int lane) {
    float tg = __int_as_float(ri.y);
    const float4 v = *reinterpret_cast<const float4*>(x + (size_t)(ri.x & (NTOT - 1)) * DF + lane * 4);
    vf4 o;
    o.x = v.x * tg; o.y = v.y * tg; o.z = v.z * tg; o.w = v.w * tg;
    __builtin_nontemporal_store(o, reinterpret_cast<vf4*>(outx + (size_t)row * DF) + lane);
    if (lane == 0) __builtin_nontemporal_store((float)(row >> 9), outb + row);
}

// fused output (tier 1): blocks [0, NROWS/4) = gather; rest = edge relabel (packed or raw)
__global__ __launch_bounds__(256) void k_out(const float* __restrict__ x,
                                             const unsigned int* __restrict__ ep,
                                             const int* __restrict__ rows,
                                             const int* __restrict__ cols,
                                             const int* __restrict__ node_map,
                                             const int2* __restrict__ rowinfo,
                                             float* __restrict__ outx,
                                             float* __restrict__ oute,
                                             float* __restrict__ outb, int E) {
    const int b = blockIdx.x, t = threadIdx.x;
    if (b < NROWS / 4) {
        int row = b * 4 + (t >> 6);
        gather_row(x, rowinfo[row], row, outx, outb, t & 63);
    } else {
        int i = (b - NROWS / 4) * 256 + t;
        if (i < E / 4) {
            if (ep) edge_body_packed(ep, node_map, oute, E, i);
            else    edge_body_raw(rows, cols, node_map, oute, E, i);
        }
    }
}

// standalone edge kernel (fallback tiers; ep safe here — consumed before gather launches)
__global__ __launch_bounds__(256) void k_edges(const unsigned int* __restrict__ ep,
                                               const int* __restrict__ node_map,
                                               float* __restrict__ oute, int E) {
    int i = blockIdx.x * blockDim.x + threadIdx.x;
    if (i < E / 4) edge_body_packed(ep, node_map, oute, E, i);
}

// uniform gather (tiers 1-2), or rows [0, LO_ROWS) in tier 3
__global__ __launch_bounds__(256) void k_gather(const float* __restrict__ x,
                                                const int2* __restrict__ rowinfo,
                                                float* __restrict__ outx,
                                                float* __restrict__ outb) {
    int row = blockIdx.x * 4 + (threadIdx.x >> 6);
    gather_row(x, rowinfo[row], row, outx, outb, threadIdx.x & 63);
}

// tier-3 tail: single workgroup, stages rowinfo tail in LDS before overwriting it
__global__ __launch_bounds__(1024) void k_gather_hi(const float* __restrict__ x,
                                                    const int2* __restrict__ rowinfo,
                                                    float* __restrict__ outx,
                                                    float* __restrict__ outb) {
    __shared__ int2 info[HI_ROWS];
    int tid = threadIdx.x;
    if (tid < HI_ROWS) info[tid] = rowinfo[LO_ROWS + tid];
    __syncthreads();
    for (int it = tid; it < HI_ROWS * 64; it += 1024) {
        int rl = it >> 6, lane = it & 63;
        gather_row(x, info[rl], LO_ROWS + rl, outx, outb, lane);
    }
}

extern "C" void kernel_launch(void* const* d_in, const int* in_sizes, int n_in,
                              void* d_out, int out_size, void* d_ws, size_t ws_size,
                              hipStream_t stream) {
    const float* x = (const float*)d_in[0];
    const int* ei = (const int*)d_in[1];
    const float* w1 = (const float*)d_in[3];
    const float* b1 = (const float*)d_in[4];
    const float* wg = (const float*)d_in[5];
    const float* bg = (const float*)d_in[6];

    const int N = in_sizes[0] / DF;        // 65536
    const int E = in_sizes[1] / 2;         // 2097152
    const int* rows = ei;
    const int* cols = ei + E;

    // FLOAT32 outputs: x_new [32768*256] | new_edge_index [2*E] | batch_new [32768]
    float* outx = (float*)d_out;
    float* oute = outx + (size_t)NROWS * DF;
    float* outb = oute + (size_t)2 * E;

    // Scratch in the front of the x_new region: sc0 | xwg | degp 1M | gcnp 4M | [ep | node_map]
    char* sb = (char*)d_out;
    float*              sc0  = (float*)(sb + 0);                      //   0 .. 256K
    float*              xwg  = (float*)(sb + (1 << 18));              // 256K .. 512K
    int*                degp = (int*)(sb + (2 << 18));                // 512K .. 1.5M
    unsigned long long* gcnp = (unsigned long long*)(sb + (6 << 18)); // 1.5M .. 5.5M

    const size_t EPBYTES = (size_t)E * 4;   // 8 MB packed edges
    int tier;
    int*  node_map;
    int2* rowinfo;
    unsigned int* ep;        // where the deg pass writes packed edges
    unsigned int* ep_out;    // what the output-stage edge relabel reads (null -> raw)
    if (ws_size >= (size_t)NTOT * 4 + (size_t)NROWS * 8 + EPBYTES) {
        tier = 1;                                     // everything in ws; fused k_out, packed
        node_map = (int*)d_ws;
        rowinfo  = (int2*)((char*)d_ws + (size_t)NTOT * 4);
        ep       = (unsigned int*)((char*)d_ws + (size_t)NTOT * 4 + (size_t)NROWS * 8);
        ep_out   = ep;
    } else if (ws_size >= (size_t)NTOT * 4 + (size_t)NROWS * 8) {
        tier = 1;                                     // fused k_out, but raw edges (ep would race)
        node_map = (int*)d_ws;
        rowinfo  = (int2*)((char*)d_ws + (size_t)NTOT * 4);
        ep       = (unsigned int*)(sb + (22 << 18));  // 5.5M .. 13.5M (pre-output use only)
        ep_out   = nullptr;
    } else if (ws_size >= (size_t)NROWS * 8) {
        tier = 2;
        node_map = (int*)(sb + (54 << 18));           // 13.5M .. 13.75M
        rowinfo  = (int2*)d_ws;
        ep       = (unsigned int*)(sb + (22 << 18));
        ep_out   = ep;                                // k_edges consumes before k_gather
    } else {
        tier = 3;
        node_map = (int*)(sb + (54 << 18));
        rowinfo  = (int2*)(sb + (size_t)NROWS * DF * 4 - (size_t)NROWS * 8);  // last 256K
        ep       = (unsigned int*)(sb + (22 << 18));
        ep_out   = ep;
    }

    hipLaunchKernelGGL(k_front, dim3(DEG_BLOCKS + DOTS_BLOCKS), dim3(256), 0, stream,
                       x, w1, wg, rows, cols, sc0, xwg, degp, ep);
    hipLaunchKernelGGL(k_gcn, dim3(NG * NB), dim3(1024), 0, stream, ep, degp, xwg, gcnp);
    hipLaunchKernelGGL(k_sort, dim3(NG), dim3(1024), 0, stream, sc0, gcnp, b1, bg, node_map, rowinfo);
    if (tier == 1) {
        hipLaunchKernelGGL(k_out, dim3(NROWS / 4 + E / 4 / 256), dim3(256), 0, stream,
                           x, ep_out, rows, cols, node_map, rowinfo, outx, oute, outb, E);
    } else if (tier == 2) {
        hipLaunchKernelGGL(k_edges, dim3(E / 4 / 256), dim3(256), 0, stream, ep_out, node_map, oute, E);
        hipLaunchKernelGGL(k_gather, dim3(NROWS / 4), dim3(256), 0, stream, x, rowinfo, outx, outb);
    } else {
        hipLaunchKernelGGL(k_edges, dim3(E / 4 / 256), dim3(256), 0, stream, ep_out, node_map, oute, E);
        hipLaunchKernelGGL(k_gather, dim3(LO_ROWS / 4), dim3(256), 0, stream, x, rowinfo, outx, outb);
        hipLaunchKernelGGL(k_gather_hi, dim3(1), dim3(1024), 0, stream, x, rowinfo, outx, outb);
    }
}